// Round 2
// baseline (2989.669 us; speedup 1.0000x reference)
//
#include <hip/hip_runtime.h>

// Problem constants
#define CDIM 64
#define HDIM 256
#define WDIM 256
#define HWSZ (HDIM * WDIM)
#define GNUM 8
#define FSZ 5

// ---------------------------------------------------------------------------
// Repack OIHW weights -> [ic][tap][oc] (contiguous in oc for uniform scalar
// loads in the conv inner loop). Also used for the 1x1 convs (TAPS=1):
// wt[ic*OC + oc] = w[oc*IC + ic].
// ---------------------------------------------------------------------------
__global__ __launch_bounds__(256) void repack_oihw(const float* __restrict__ w,
                                                   float* __restrict__ wt,
                                                   int OC, int IC, int TAPS) {
    int idx = blockIdx.x * 256 + threadIdx.x;
    int total = OC * IC * TAPS;
    if (idx >= total) return;
    int oc  = idx / (IC * TAPS);
    int rem = idx - oc * (IC * TAPS);
    int ic  = rem / TAPS;
    int tap = rem - ic * TAPS;
    wt[(ic * TAPS + tap) * OC + oc] = w[idx];
}

// ---------------------------------------------------------------------------
// Direct KSxKS conv, 64->64 channels, stride 1, SAME padding.
// Block = 256 threads = 16x16 output pixels; each thread accumulates all 64
// output channels. Input staged in LDS 16 channels at a time. Weights are
// pre-repacked to [ic][tap][64] so wp[oc] is a contiguous uniform load.
// ---------------------------------------------------------------------------
template <int KS, bool PRELU, bool RESID>
__global__ __launch_bounds__(256) void convk(const float* __restrict__ in,
                                             const float* __restrict__ wt,
                                             const float* __restrict__ bias,
                                             const float* __restrict__ alpha,
                                             const float* __restrict__ resid,
                                             float* __restrict__ out) {
    constexpr int PADK = (KS - 1) / 2;
    constexpr int IT   = 16 + KS - 1;   // staged tile edge (20 or 18)
    constexpr int ICC  = 16;            // input channels per LDS chunk

    __shared__ float lds[ICC * IT * IT];

    const int b   = blockIdx.z;
    const int tx0 = blockIdx.x * 16;
    const int ty0 = blockIdx.y * 16;
    const int tid = threadIdx.x;
    const int lx  = tid & 15;
    const int ly  = tid >> 4;

    float acc[CDIM];
#pragma unroll
    for (int i = 0; i < CDIM; ++i) acc[i] = 0.f;

    const float* inb = in + (size_t)b * CDIM * HWSZ;

    for (int icc = 0; icc < CDIM; icc += ICC) {
        __syncthreads();  // protect LDS reuse from previous chunk
        // stage ICC channels of the (16+KS-1)^2 input tile
        for (int i = tid; i < ICC * IT * IT; i += 256) {
            int ic  = i / (IT * IT);
            int rem = i - ic * (IT * IT);
            int yy  = rem / IT;
            int xx  = rem - yy * IT;
            int gy  = ty0 - PADK + yy;
            int gx  = tx0 - PADK + xx;
            float v = 0.f;
            if (gy >= 0 && gy < HDIM && gx >= 0 && gx < WDIM)
                v = inb[(size_t)(icc + ic) * HWSZ + gy * WDIM + gx];
            lds[i] = v;
        }
        __syncthreads();

        for (int tap = 0; tap < KS * KS; ++tap) {
            const int dy = tap / KS;
            const int dx = tap - dy * KS;
            for (int ic = 0; ic < ICC; ++ic) {
                float v = lds[ic * IT * IT + (ly + dy) * IT + (lx + dx)];
                const float* wp = wt + ((size_t)(icc + ic) * KS * KS + tap) * CDIM;
#pragma unroll
                for (int oc = 0; oc < CDIM; ++oc)
                    acc[oc] = fmaf(v, wp[oc], acc[oc]);
            }
        }
    }

    const int ox = tx0 + lx;
    const int oy = ty0 + ly;
    const size_t pix = (size_t)oy * WDIM + ox;
#pragma unroll
    for (int oc = 0; oc < CDIM; ++oc) {
        float v = acc[oc] + bias[oc];
        if constexpr (PRELU) {
            float a = alpha[0];
            v = (v >= 0.f) ? v : a * v;
        }
        if constexpr (RESID) {
            v += resid[((size_t)b * CDIM + oc) * HWSZ + pix];
        }
        out[((size_t)b * CDIM + oc) * HWSZ + pix] = v;
    }
}

// ---------------------------------------------------------------------------
// Fused: per-pixel bilateral kernel (two 1x1 convs 64->200, elementwise
// product) + grouped 25-tap apply on source patches.
// Block = 256 threads = 16x16 pixels. Loop over the 8 groups; per group the
// 8 source channels' (16+4)^2 tile is staged in LDS.
// wt3t/wt3g are repacked to [ic][200] (contiguous over the 25 taps of a group).
// ---------------------------------------------------------------------------
__global__ __launch_bounds__(256) void jbf_fused(const float* __restrict__ r2,
                                                 const float* __restrict__ g2,
                                                 const float* __restrict__ src,
                                                 const float* __restrict__ wt3t,
                                                 const float* __restrict__ tb3,
                                                 const float* __restrict__ wt3g,
                                                 const float* __restrict__ gb3,
                                                 float* __restrict__ out) {
    constexpr int IT = 20;  // 16 + FSZ - 1
    __shared__ float sSrc[8 * IT * IT];

    const int b   = blockIdx.z;
    const int tx0 = blockIdx.x * 16;
    const int ty0 = blockIdx.y * 16;
    const int tid = threadIdx.x;
    const int lx  = tid & 15;
    const int ly  = tid >> 4;

    const size_t pix = (size_t)(ty0 + ly) * WDIM + (tx0 + lx);
    const float* r2b  = r2  + (size_t)b * CDIM * HWSZ;
    const float* g2b  = g2  + (size_t)b * CDIM * HWSZ;
    const float* srcb = src + (size_t)b * CDIM * HWSZ;

    for (int g = 0; g < GNUM; ++g) {
        __syncthreads();
        // stage the 8 source channels of this group (20x20 tile, zero-padded)
        for (int i = tid; i < 8 * IT * IT; i += 256) {
            int c   = i / (IT * IT);
            int rem = i - c * (IT * IT);
            int yy  = rem / IT;
            int xx  = rem - yy * IT;
            int gy  = ty0 - 2 + yy;
            int gx  = tx0 - 2 + xx;
            float v = 0.f;
            if (gy >= 0 && gy < HDIM && gx >= 0 && gx < WDIM)
                v = srcb[(size_t)(g * 8 + c) * HWSZ + gy * WDIM + gx];
            sSrc[i] = v;
        }
        __syncthreads();

        // two 1x1 convs (64 -> 25 taps of this group), then product
        float kt[25], kg[25];
#pragma unroll
        for (int t = 0; t < 25; ++t) {
            kt[t] = tb3[g * 25 + t];
            kg[t] = gb3[g * 25 + t];
        }
        for (int ic = 0; ic < CDIM; ++ic) {
            float vr = r2b[(size_t)ic * HWSZ + pix];
            float vg = g2b[(size_t)ic * HWSZ + pix];
            const float* wpt = wt3t + (size_t)ic * 200 + g * 25;
            const float* wpg = wt3g + (size_t)ic * 200 + g * 25;
#pragma unroll
            for (int t = 0; t < 25; ++t) {
                kt[t] = fmaf(vr, wpt[t], kt[t]);
                kg[t] = fmaf(vg, wpg[t], kg[t]);
            }
        }
#pragma unroll
        for (int t = 0; t < 25; ++t) kt[t] *= kg[t];  // ker = kt * kg

        // apply the 25-tap kernel to the 8 channels of this group
#pragma unroll
        for (int c = 0; c < 8; ++c) {
            float a = 0.f;
#pragma unroll
            for (int t = 0; t < 25; ++t) {
                int dy = t / 5, dx = t - dy * 5;
                a = fmaf(kt[t], sSrc[c * IT * IT + (ly + dy) * IT + (lx + dx)], a);
            }
            out[((size_t)b * CDIM + g * 8 + c) * HWSZ + pix] = a;
        }
    }
}

// ---------------------------------------------------------------------------
extern "C" void kernel_launch(void* const* d_in, const int* in_sizes, int n_in,
                              void* d_out, int out_size, void* d_ws, size_t ws_size,
                              hipStream_t stream) {
    const float* source   = (const float*)d_in[0];
    const float* guidance = (const float*)d_in[1];
    const float* t_w1 = (const float*)d_in[2];
    const float* t_b1 = (const float*)d_in[3];
    const float* t_a1 = (const float*)d_in[4];
    const float* t_w2 = (const float*)d_in[5];
    const float* t_b2 = (const float*)d_in[6];
    const float* t_a2 = (const float*)d_in[7];
    const float* t_w3 = (const float*)d_in[8];
    const float* t_b3 = (const float*)d_in[9];
    const float* g_w1 = (const float*)d_in[10];
    const float* g_b1 = (const float*)d_in[11];
    const float* g_a1 = (const float*)d_in[12];
    const float* g_w2 = (const float*)d_in[13];
    const float* g_b2 = (const float*)d_in[14];
    const float* g_a2 = (const float*)d_in[15];
    const float* g_w3 = (const float*)d_in[16];
    const float* g_b3 = (const float*)d_in[17];
    const float* j_w1 = (const float*)d_in[18];
    const float* j_b1 = (const float*)d_in[19];
    const float* j_a1 = (const float*)d_in[20];
    const float* j_w2 = (const float*)d_in[21];
    const float* j_b2 = (const float*)d_in[22];
    float* out = (float*)d_out;

    // workspace layout (floats). d_out doubles as scratch for g2 (it is fully
    // written by conv-g2 before jbf_fused reads it, then fully overwritten by
    // the final conv) -> only 2 ws planes (~66 MB) needed.
    const size_t planeN = (size_t)2 * CDIM * HWSZ;  // 8388608 floats = 32 MB
    float* ws    = (float*)d_ws;
    float* bufA  = ws;
    float* bufB  = bufA + planeN;
    float* wt_t1 = bufB + planeN;            // 64*64*25 = 102400
    float* wt_t2 = wt_t1 + 102400;
    float* wt_g1 = wt_t2 + 102400;
    float* wt_g2 = wt_g1 + 102400;
    float* wt_j1 = wt_g2 + 102400;           // 64*64*9 = 36864
    float* wt_j2 = wt_j1 + 36864;
    float* wt_t3 = wt_j2 + 36864;            // 64*200 = 12800
    float* wt_g3 = wt_t3 + 12800;

    // --- repack weights ---
    repack_oihw<<<(64 * 64 * 25 + 255) / 256, 256, 0, stream>>>(t_w1, wt_t1, 64, 64, 25);
    repack_oihw<<<(64 * 64 * 25 + 255) / 256, 256, 0, stream>>>(t_w2, wt_t2, 64, 64, 25);
    repack_oihw<<<(64 * 64 * 25 + 255) / 256, 256, 0, stream>>>(g_w1, wt_g1, 64, 64, 25);
    repack_oihw<<<(64 * 64 * 25 + 255) / 256, 256, 0, stream>>>(g_w2, wt_g2, 64, 64, 25);
    repack_oihw<<<(64 * 64 * 9 + 255) / 256, 256, 0, stream>>>(j_w1, wt_j1, 64, 64, 9);
    repack_oihw<<<(64 * 64 * 9 + 255) / 256, 256, 0, stream>>>(j_w2, wt_j2, 64, 64, 9);
    repack_oihw<<<(200 * 64 + 255) / 256, 256, 0, stream>>>(t_w3, wt_t3, 200, 64, 1);
    repack_oihw<<<(200 * 64 + 255) / 256, 256, 0, stream>>>(g_w3, wt_g3, 200, 64, 1);

    dim3 grid(WDIM / 16, HDIM / 16, 2);
    dim3 block(256);

    // target KG: r1 = prelu(conv5(source)) -> A; r2 = prelu(conv5(r1)) -> B
    convk<5, true, false><<<grid, block, 0, stream>>>(source, wt_t1, t_b1, t_a1, nullptr, bufA);
    convk<5, true, false><<<grid, block, 0, stream>>>(bufA, wt_t2, t_b2, t_a2, nullptr, bufB);
    // guidance KG: g1 -> A; g2 -> out (scratch)
    convk<5, true, false><<<grid, block, 0, stream>>>(guidance, wt_g1, g_b1, g_a1, nullptr, bufA);
    convk<5, true, false><<<grid, block, 0, stream>>>(bufA, wt_g2, g_b2, g_a2, nullptr, out);

    // fused bilateral kernel + grouped apply -> A
    jbf_fused<<<grid, block, 0, stream>>>(bufB, out, source, wt_t3, t_b3, wt_g3, g_b3, bufA);

    // output conv pair + residual
    convk<3, true, false><<<grid, block, 0, stream>>>(bufA, wt_j1, j_b1, j_a1, nullptr, bufB);
    convk<3, false, true><<<grid, block, 0, stream>>>(bufB, wt_j2, j_b2, nullptr, source, out);
}

// Round 3
// 724.181 us; speedup vs baseline: 4.1283x; 4.1283x over previous
//
#include <hip/hip_runtime.h>

#define CDIM 64
#define HDIM 256
#define WDIM 256
#define HWSZ (HDIM * WDIM)
#define GNUM 8

typedef _Float16 f16;
typedef f16  f16x8  __attribute__((ext_vector_type(8)));
typedef float f32x4 __attribute__((ext_vector_type(4)));

static __device__ __forceinline__ ushort f16bits(float v) {
    f16 h = (f16)v;
    return __builtin_bit_cast(ushort, h);
}

// ---------------------------------------------------------------------------
// Repack OIHW f32 -> [tap][oc][ic] f16 (ic contiguous -> 16B chunks for LDS).
// ---------------------------------------------------------------------------
__global__ __launch_bounds__(256) void repack_wf16(const float* __restrict__ w,
                                                   ushort* __restrict__ wt, int TAPS) {
    int idx = blockIdx.x * 256 + threadIdx.x;
    int total = 64 * 64 * TAPS;
    if (idx >= total) return;
    int tap = idx / 4096;
    int rem = idx - tap * 4096;
    int oc = rem >> 6, ic = rem & 63;
    wt[idx] = f16bits(w[(oc * 64 + ic) * TAPS + tap]);
}

// Repack OIHW f32 -> [ic][OC] f32 (for the 1x1 convs; uniform scalar loads).
__global__ __launch_bounds__(256) void repack_oihw(const float* __restrict__ w,
                                                   float* __restrict__ wt,
                                                   int OC, int IC) {
    int idx = blockIdx.x * 256 + threadIdx.x;
    if (idx >= OC * IC) return;
    int oc = idx / IC, ic = idx - oc * IC;
    wt[ic * OC + oc] = w[idx];
}

// ---------------------------------------------------------------------------
// Implicit-GEMM conv via MFMA f16 (f32 accumulate).
//   D[m=pix][n=oc] = sum_{tap,ic} A[pix][ic](shifted) * W_tap[oc][ic]
// Block: 256 thr = 4 waves, out tile 32x x 8y pixels, all 64 oc.
// Wave w: x0=(w&1)*16, y0=(w>>1)*4; 4 M-tiles (rows) x 4 N-tiles (oc16).
// Input staged once in LDS as [pix][64ch] f16, 16B chunks XOR-swizzled by x&7.
// Weights staged per tap (8KB) XOR-swizzled by oc&7.
// mfma_f32_16x16x32_f16 fragment layout:
//   A: lane reads A[m=lane&15][k=(lane>>4)*8 + 0..7]
//   B: lane reads W[oc=lane&15][ic=(lane>>4)*8 + 0..7]   (B^T layout)
//   D: lane holds D[m=(lane>>4)*4 + r][n=lane&15]
// ---------------------------------------------------------------------------
template <int KS, bool IN_F32_NCHW, bool PRELU, bool F32OUT>
__global__ __launch_bounds__(256, 2) void conv_mfma(
        const void* __restrict__ inp,
        const ushort* __restrict__ wt,     // f16 [tap][64][64]
        const float* __restrict__ bias,
        const float* __restrict__ alpha,
        const float* __restrict__ resid,   // f32 NCHW (F32OUT only)
        void* __restrict__ outp) {
    constexpr int H  = KS / 2;
    constexpr int TX = 32, TY = 8;
    constexpr int IX = TX + 2 * H, IY = TY + 2 * H;
    constexpr int NP = IX * IY;

    __shared__ __align__(16) ushort sX[NP * 64];
    __shared__ __align__(16) ushort sW[64 * 64];

    const int b    = blockIdx.z;
    const int bx   = blockIdx.x * TX;
    const int by   = blockIdx.y * TY;
    const int tid  = threadIdx.x;
    const int lane = tid & 63;
    const int wv   = tid >> 6;
    const int x0w  = (wv & 1) * 16;
    const int y0w  = (wv >> 1) * 4;
    const int lr   = lane & 15;   // fragment row/col lane index
    const int hi   = lane >> 4;   // k-group / row-group

    // ---- stage input tile ----
    if constexpr (IN_F32_NCHW) {
        const float* inf = (const float*)inp + (size_t)b * CDIM * HWSZ;
        for (int i = tid; i < CDIM * NP; i += 256) {
            int ch = i / NP, p = i - ch * NP;
            int iy = p / IX, ix = p - iy * IX;
            int gy = by - H + iy, gx = bx - H + ix;
            float v = 0.f;
            if (gy >= 0 && gy < HDIM && gx >= 0 && gx < WDIM)
                v = inf[ch * HWSZ + gy * WDIM + gx];
            int chunk = (ch >> 3) ^ (ix & 7);
            sX[p * 64 + chunk * 8 + (ch & 7)] = f16bits(v);
        }
    } else {
        const ushort* inh = (const ushort*)inp + (size_t)b * HWSZ * 64;
        for (int i = tid; i < NP * 8; i += 256) {
            int p = i >> 3, chunk = i & 7;
            int iy = p / IX, ix = p - iy * IX;
            int gy = by - H + iy, gx = bx - H + ix;
            uint4 v = make_uint4(0u, 0u, 0u, 0u);
            if (gy >= 0 && gy < HDIM && gx >= 0 && gx < WDIM)
                v = *(const uint4*)(inh + ((size_t)(gy * WDIM + gx)) * 64 + chunk * 8);
            *(uint4*)((char*)sX + p * 128 + ((chunk ^ (ix & 7)) << 4)) = v;
        }
    }

    f32x4 acc[4][4] = {};

    for (int tap = 0; tap < KS * KS; ++tap) {
        __syncthreads();
        // stage this tap's 64x64 f16 weights (8KB), swizzled by oc&7
        {
            const uint4* wsrc = (const uint4*)(wt + (size_t)tap * 4096);
            for (int i = tid; i < 512; i += 256) {
                int oc = i >> 3, chunk = i & 7;
                uint4 v = wsrc[i];
                *(uint4*)((char*)sW + oc * 128 + ((chunk ^ (oc & 7)) << 4)) = v;
            }
        }
        __syncthreads();
        const int dy = tap / KS, dx = tap - dy * KS;

#pragma unroll
        for (int ks = 0; ks < 2; ++ks) {
            f16x8 afr[4], bfr[4];
#pragma unroll
            for (int mt = 0; mt < 4; ++mt) {
                int iy = y0w + mt + dy;
                int ix = x0w + dx + lr;
                int chunk = (ks * 4 + hi) ^ (ix & 7);
                afr[mt] = *(const f16x8*)((const char*)sX + (iy * IX + ix) * 128 + (chunk << 4));
            }
#pragma unroll
            for (int nt = 0; nt < 4; ++nt) {
                int oc = nt * 16 + lr;
                int chunk = (ks * 4 + hi) ^ (oc & 7);
                bfr[nt] = *(const f16x8*)((const char*)sW + oc * 128 + (chunk << 4));
            }
#pragma unroll
            for (int mt = 0; mt < 4; ++mt)
#pragma unroll
                for (int nt = 0; nt < 4; ++nt)
                    acc[mt][nt] = __builtin_amdgcn_mfma_f32_16x16x32_f16(
                        afr[mt], bfr[nt], acc[mt][nt], 0, 0, 0);
        }
    }

    // ---- epilogue ----
    const float al = PRELU ? alpha[0] : 0.f;
#pragma unroll
    for (int nt = 0; nt < 4; ++nt) {
        const int oc = nt * 16 + lr;
        const float bs = bias[oc];
#pragma unroll
        for (int mt = 0; mt < 4; ++mt) {
            const int gy = by + y0w + mt;
            const int gxb = bx + x0w + hi * 4;
            if constexpr (!F32OUT) {
                ushort* o = (ushort*)outp + (size_t)b * HWSZ * 64;
#pragma unroll
                for (int r = 0; r < 4; ++r) {
                    float v = acc[mt][nt][r] + bs;
                    if constexpr (PRELU) v = (v >= 0.f) ? v : al * v;
                    o[((size_t)(gy * WDIM + gxb + r)) * 64 + oc] = f16bits(v);
                }
            } else {
                float* o = (float*)outp;
                size_t base = ((size_t)(b * CDIM + oc)) * HWSZ + gy * WDIM + gxb;
                float4 sv = *(const float4*)(resid + base);
                float4 ov;
                ov.x = acc[mt][nt][0] + bs + sv.x;
                ov.y = acc[mt][nt][1] + bs + sv.y;
                ov.z = acc[mt][nt][2] + bs + sv.z;
                ov.w = acc[mt][nt][3] + bs + sv.w;
                *(float4*)(o + base) = ov;
            }
        }
    }
}

// ---------------------------------------------------------------------------
// Fused bilateral kernel: two 1x1 convs (64 -> 25 taps per group) + product +
// grouped 25-tap apply on f32 NCHW source patches. r2/g2 are f16 NHWC.
// Output: f16 NHWC (registered, 16B stores).
// ---------------------------------------------------------------------------
__global__ __launch_bounds__(256) void jbf_fused(const f16* __restrict__ r2,
                                                 const f16* __restrict__ g2,
                                                 const float* __restrict__ src,
                                                 const float* __restrict__ wt3t,
                                                 const float* __restrict__ tb3,
                                                 const float* __restrict__ wt3g,
                                                 const float* __restrict__ gb3,
                                                 ushort* __restrict__ out) {
    constexpr int IT = 20;  // 16 + 4
    __shared__ float sSrc[8 * IT * IT];

    const int b   = blockIdx.z;
    const int tx0 = blockIdx.x * 16;
    const int ty0 = blockIdx.y * 16;
    const int tid = threadIdx.x;
    const int lx  = tid & 15;
    const int ly  = tid >> 4;

    const size_t pix = (size_t)(ty0 + ly) * WDIM + (tx0 + lx);
    const f16*  r2b  = r2 + (size_t)b * HWSZ * 64;
    const f16*  g2b  = g2 + (size_t)b * HWSZ * 64;
    const float* srcb = src + (size_t)b * CDIM * HWSZ;

    float jout[64];

    for (int g = 0; g < GNUM; ++g) {
        __syncthreads();
        for (int i = tid; i < 8 * IT * IT; i += 256) {
            int c   = i / (IT * IT);
            int rem = i - c * (IT * IT);
            int yy  = rem / IT;
            int xx  = rem - yy * IT;
            int gy  = ty0 - 2 + yy;
            int gx  = tx0 - 2 + xx;
            float v = 0.f;
            if (gy >= 0 && gy < HDIM && gx >= 0 && gx < WDIM)
                v = srcb[(size_t)(g * 8 + c) * HWSZ + gy * WDIM + gx];
            sSrc[i] = v;
        }
        __syncthreads();

        float kt[25], kg[25];
#pragma unroll
        for (int t = 0; t < 25; ++t) {
            kt[t] = tb3[g * 25 + t];
            kg[t] = gb3[g * 25 + t];
        }
        for (int icv = 0; icv < 8; ++icv) {
            f16x8 rv = *(const f16x8*)(r2b + pix * 64 + icv * 8);
            f16x8 gv = *(const f16x8*)(g2b + pix * 64 + icv * 8);
#pragma unroll
            for (int j = 0; j < 8; ++j) {
                float vr = (float)rv[j];
                float vg = (float)gv[j];
                const int ic = icv * 8 + j;
                const float* wpt = wt3t + ic * 200 + g * 25;
                const float* wpg = wt3g + ic * 200 + g * 25;
#pragma unroll
                for (int t = 0; t < 25; ++t) {
                    kt[t] = fmaf(vr, wpt[t], kt[t]);
                    kg[t] = fmaf(vg, wpg[t], kg[t]);
                }
            }
        }
#pragma unroll
        for (int t = 0; t < 25; ++t) kt[t] *= kg[t];

#pragma unroll
        for (int c = 0; c < 8; ++c) {
            float a = 0.f;
#pragma unroll
            for (int t = 0; t < 25; ++t) {
                int dy = t / 5, dx = t - dy * 5;
                a = fmaf(kt[t], sSrc[c * IT * IT + (ly + dy) * IT + (lx + dx)], a);
            }
            jout[g * 8 + c] = a;
        }
    }

    ushort* ob = out + (size_t)b * HWSZ * 64;
#pragma unroll
    for (int c8 = 0; c8 < 8; ++c8) {
        f16x8 h;
#pragma unroll
        for (int j = 0; j < 8; ++j) h[j] = (f16)jout[c8 * 8 + j];
        *(uint4*)(ob + pix * 64 + c8 * 8) = __builtin_bit_cast(uint4, h);
    }
}

// ---------------------------------------------------------------------------
extern "C" void kernel_launch(void* const* d_in, const int* in_sizes, int n_in,
                              void* d_out, int out_size, void* d_ws, size_t ws_size,
                              hipStream_t stream) {
    const float* source   = (const float*)d_in[0];
    const float* guidance = (const float*)d_in[1];
    const float* t_w1 = (const float*)d_in[2];
    const float* t_b1 = (const float*)d_in[3];
    const float* t_a1 = (const float*)d_in[4];
    const float* t_w2 = (const float*)d_in[5];
    const float* t_b2 = (const float*)d_in[6];
    const float* t_a2 = (const float*)d_in[7];
    const float* t_w3 = (const float*)d_in[8];
    const float* t_b3 = (const float*)d_in[9];
    const float* g_w1 = (const float*)d_in[10];
    const float* g_b1 = (const float*)d_in[11];
    const float* g_a1 = (const float*)d_in[12];
    const float* g_w2 = (const float*)d_in[13];
    const float* g_b2 = (const float*)d_in[14];
    const float* g_a2 = (const float*)d_in[15];
    const float* g_w3 = (const float*)d_in[16];
    const float* g_b3 = (const float*)d_in[17];
    const float* j_w1 = (const float*)d_in[18];
    const float* j_b1 = (const float*)d_in[19];
    const float* j_a1 = (const float*)d_in[20];
    const float* j_w2 = (const float*)d_in[21];
    const float* j_b2 = (const float*)d_in[22];

    // workspace layout: two f16 NHWC activation planes + repacked weights.
    // d_out (33.5 MB) doubles as the g2 f16 plane before the final f32 write.
    const size_t planeH = (size_t)2 * HWSZ * 64;  // 16.7M f16 elems
    ushort* bufA  = (ushort*)d_ws;
    ushort* bufB  = bufA + planeH;
    ushort* wt_t1 = bufB + planeH;                 // 25*4096 each
    ushort* wt_t2 = wt_t1 + 102400;
    ushort* wt_g1 = wt_t2 + 102400;
    ushort* wt_g2 = wt_g1 + 102400;
    ushort* wt_j1 = wt_g2 + 102400;                // 9*4096
    ushort* wt_j2 = wt_j1 + 36864;
    float*  wt_t3 = (float*)(wt_j2 + 36864);       // [64][200] f32
    float*  wt_g3 = wt_t3 + 12800;
    ushort* bufC  = (ushort*)d_out;                // g2 scratch (f16 NHWC)

    repack_wf16<<<(64 * 64 * 25 + 255) / 256, 256, 0, stream>>>(t_w1, wt_t1, 25);
    repack_wf16<<<(64 * 64 * 25 + 255) / 256, 256, 0, stream>>>(t_w2, wt_t2, 25);
    repack_wf16<<<(64 * 64 * 25 + 255) / 256, 256, 0, stream>>>(g_w1, wt_g1, 25);
    repack_wf16<<<(64 * 64 * 25 + 255) / 256, 256, 0, stream>>>(g_w2, wt_g2, 25);
    repack_wf16<<<(64 * 64 * 9 + 255) / 256, 256, 0, stream>>>(j_w1, wt_j1, 9);
    repack_wf16<<<(64 * 64 * 9 + 255) / 256, 256, 0, stream>>>(j_w2, wt_j2, 9);
    repack_oihw<<<(200 * 64 + 255) / 256, 256, 0, stream>>>(t_w3, wt_t3, 200, 64);
    repack_oihw<<<(200 * 64 + 255) / 256, 256, 0, stream>>>(g_w3, wt_g3, 200, 64);

    dim3 cgrid(WDIM / 32, HDIM / 8, 2);
    dim3 blk(256);

    // t1: source(f32 NCHW) -> A ; t2: A -> B  (r2)
    conv_mfma<5, true,  true,  false><<<cgrid, blk, 0, stream>>>(source,  wt_t1, t_b1, t_a1, nullptr, bufA);
    conv_mfma<5, false, true,  false><<<cgrid, blk, 0, stream>>>(bufA,    wt_t2, t_b2, t_a2, nullptr, bufB);
    // g1: guidance -> A ; g2: A -> C(d_out)  (g2)
    conv_mfma<5, true,  true,  false><<<cgrid, blk, 0, stream>>>(guidance, wt_g1, g_b1, g_a1, nullptr, bufA);
    conv_mfma<5, false, true,  false><<<cgrid, blk, 0, stream>>>(bufA,    wt_g2, g_b2, g_a2, nullptr, bufC);

    // fused bilateral kernel + apply -> A
    dim3 jgrid(WDIM / 16, HDIM / 16, 2);
    jbf_fused<<<jgrid, blk, 0, stream>>>((const f16*)bufB, (const f16*)bufC, source,
                                         wt_t3, t_b3, wt_g3, g_b3, bufA);

    // j1: A -> B ; j2: B -> d_out (f32 NCHW, + source residual)
    conv_mfma<3, false, true,  false><<<cgrid, blk, 0, stream>>>(bufA, wt_j1, j_b1, j_a1, nullptr, bufB);
    conv_mfma<3, false, false, true ><<<cgrid, blk, 0, stream>>>(bufB, wt_j2, j_b2, nullptr, source, d_out);
}